// Round 5
// baseline (209.366 us; speedup 1.0000x reference)
//
#include <hip/hip_runtime.h>
#include <hip/hip_cooperative_groups.h>

namespace cg = cooperative_groups;

#define BB 2
#define SS 2048
#define DD 1024
#define NBLK 256
#define NTHR 256
// 4096 total rows (b*2048+s) / 256 blocks = 16 rows per block; blocks 0..127 -> b=0, 128..255 -> b=1
#define ROWS_PER_BLK 16

// ws layout (floats): partial[256][1024] | hbar[2][1024] | vmean[2][1024] | orow[2][1024]
__global__ void __launch_bounds__(NTHR, 1)
fused_kernel(const float* __restrict__ h, const float* __restrict__ Wv,
             const float* __restrict__ Wo, float* __restrict__ out,
             float* __restrict__ ws) {
    cg::grid_group grid = cg::this_grid();

    float* partial = ws;                       // 256*1024
    float* hbar    = ws + NBLK * DD;           // 2048
    float* vmean   = hbar + BB * DD;           // 2048
    float* orow    = vmean + BB * DD;          // 2048

    const int bid = blockIdx.x;
    const int tid = threadIdx.x;
    const int gtid = bid * NTHR + tid;         // 0..65535
    const int lane = tid & 63;
    const int wave = gtid >> 6;                // 0..1023

    // ---- Phase 1: per-block partial column sums (16 rows each, single batch per block)
    {
        const float4* hp = reinterpret_cast<const float4*>(h);
        float4 acc = make_float4(0.f, 0.f, 0.f, 0.f);
        int r0 = bid * ROWS_PER_BLK;           // flattened row index (b*SS + s)
        #pragma unroll 4
        for (int r = r0; r < r0 + ROWS_PER_BLK; ++r) {
            float4 v = hp[(size_t)r * (DD / 4) + tid];
            acc.x += v.x; acc.y += v.y; acc.z += v.z; acc.w += v.w;
        }
        reinterpret_cast<float4*>(partial)[bid * (DD / 4) + tid] = acc;
    }
    grid.sync();

    // ---- Phase 1b: reduce 128 partials per batch -> hbar[b][d]  (first 2048 threads)
    if (gtid < BB * DD) {
        int b = gtid >> 10;
        int d = gtid & (DD - 1);
        float s = 0.f;
        #pragma unroll 8
        for (int j = 0; j < 128; ++j)
            s += partial[(size_t)(b * 128 + j) * DD + d];
        hbar[gtid] = s;
    }
    grid.sync();

    // ---- Phase 2: vmean[o] = dot(Wv[i,:], hbar[b,:]) / SS   (1024 waves x 2 outputs)
    {
        #pragma unroll
        for (int rep = 0; rep < 2; ++rep) {
            int o = wave + rep * 1024;         // 0..2047
            int b = o >> 10;
            int i = o & (DD - 1);
            const float4* Wp = reinterpret_cast<const float4*>(Wv + (size_t)i * DD);
            const float4* xp = reinterpret_cast<const float4*>(hbar + b * DD);
            float sum = 0.f;
            #pragma unroll
            for (int k4 = lane; k4 < DD / 4; k4 += 64) {
                float4 w = Wp[k4];
                float4 x = xp[k4];
                sum += w.x * x.x + w.y * x.y + w.z * x.z + w.w * x.w;
            }
            #pragma unroll
            for (int off = 32; off > 0; off >>= 1) sum += __shfl_down(sum, off);
            if (lane == 0) vmean[o] = sum * (1.0f / (float)SS);
        }
    }
    grid.sync();

    // ---- Phase 3: orow[o] = dot(Wo[i,:], vmean[b,:])
    {
        #pragma unroll
        for (int rep = 0; rep < 2; ++rep) {
            int o = wave + rep * 1024;
            int b = o >> 10;
            int i = o & (DD - 1);
            const float4* Wp = reinterpret_cast<const float4*>(Wo + (size_t)i * DD);
            const float4* xp = reinterpret_cast<const float4*>(vmean + b * DD);
            float sum = 0.f;
            #pragma unroll
            for (int k4 = lane; k4 < DD / 4; k4 += 64) {
                float4 w = Wp[k4];
                float4 x = xp[k4];
                sum += w.x * x.x + w.y * x.y + w.z * x.z + w.w * x.w;
            }
            #pragma unroll
            for (int off = 32; off > 0; off >>= 1) sum += __shfl_down(sum, off);
            if (lane == 0) orow[o] = sum;
        }
    }
    grid.sync();

    // ---- Phase 4: out[b][s][:] = orow[b][:]   (broadcast, float4 stores)
    {
        const float4* r4 = reinterpret_cast<const float4*>(orow);
        float4* o4 = reinterpret_cast<float4*>(out);
        const int total4 = BB * SS * (DD / 4); // 1,048,576
        for (int i = gtid; i < total4; i += NBLK * NTHR) {
            int d4 = i & (DD / 4 - 1);
            int b = i >> 19;
            o4[i] = r4[b * (DD / 4) + d4];
        }
    }
}

extern "C" void kernel_launch(void* const* d_in, const int* in_sizes, int n_in,
                              void* d_out, int out_size, void* d_ws, size_t ws_size,
                              hipStream_t stream) {
    const float* h  = (const float*)d_in[0];   // hidden_states [2,2048,1024]
    const float* Wv = (const float*)d_in[3];   // [1024,1024]
    const float* Wo = (const float*)d_in[4];   // [1024,1024]
    float* out = (float*)d_out;                // [2,2048,1024]
    float* ws  = (float*)d_ws;

    void* args[] = { (void*)&h, (void*)&Wv, (void*)&Wo, (void*)&out, (void*)&ws };
    hipLaunchCooperativeKernel((const void*)fused_kernel, dim3(NBLK), dim3(NTHR),
                               args, 0, stream);
}

// Round 6
// 115.539 us; speedup vs baseline: 1.8121x; 1.8121x over previous
//
#include <hip/hip_runtime.h>

#define BB 2
#define SS 2048
#define DD 1024   // == INNER

// K1: partial[b*64+chunk][1024] = sum of 32 rows of h.  128 blocks x 256 thr.
__global__ void colsum_kernel(const float* __restrict__ h, float* __restrict__ partial) {
    int bid = blockIdx.x;            // 0..127
    int b = bid >> 6;                // 0..1
    int chunk = bid & 63;            // 0..63
    int t = threadIdx.x;             // 0..255 (one float4 column each)
    const float4* hp = reinterpret_cast<const float4*>(h) + (size_t)b * SS * (DD / 4);
    float4 acc = make_float4(0.f, 0.f, 0.f, 0.f);
    int s0 = chunk * 32;
    #pragma unroll 4
    for (int s = s0; s < s0 + 32; ++s) {
        float4 v = hp[(size_t)s * (DD / 4) + t];
        acc.x += v.x; acc.y += v.y; acc.z += v.z; acc.w += v.w;
    }
    reinterpret_cast<float4*>(partial)[(size_t)bid * (DD / 4) + t] = acc;
}

// K2: per-block reduce partial -> hbar (LDS), then vmean[b][i] = dot(Wv[i,:],hbar[b,:])/SS
// 32 blocks x 256 thr; block bid owns i in [bid*32, bid*32+32), both b.
__global__ void matvec1_kernel(const float* __restrict__ Wv, const float* __restrict__ partial,
                               float* __restrict__ vmean) {
    __shared__ float4 hbar4[2 * (DD / 4)];   // [b*256 + c]
    int t = threadIdx.x;
    const float4* p4 = reinterpret_cast<const float4*>(partial);
    float4 a0 = make_float4(0.f, 0.f, 0.f, 0.f);
    float4 a1 = make_float4(0.f, 0.f, 0.f, 0.f);
    #pragma unroll 8
    for (int j = 0; j < 64; ++j) {
        float4 v0 = p4[(size_t)j * (DD / 4) + t];
        float4 v1 = p4[(size_t)(64 + j) * (DD / 4) + t];
        a0.x += v0.x; a0.y += v0.y; a0.z += v0.z; a0.w += v0.w;
        a1.x += v1.x; a1.y += v1.y; a1.z += v1.z; a1.w += v1.w;
    }
    hbar4[t] = a0;
    hbar4[256 + t] = a1;
    __syncthreads();

    int wv = t >> 6, lane = t & 63;
    int i0 = blockIdx.x * 32;
    #pragma unroll
    for (int r = 0; r < 16; ++r) {
        int ol = wv * 16 + r;            // 0..63
        int il = ol >> 1, b = ol & 1;
        int i = i0 + il;
        const float4* Wp = reinterpret_cast<const float4*>(Wv) + (size_t)i * (DD / 4);
        float sum = 0.f;
        #pragma unroll
        for (int p = 0; p < 4; ++p) {
            float4 w = Wp[lane + p * 64];
            float4 x = hbar4[b * 256 + lane + p * 64];
            sum += w.x * x.x + w.y * x.y + w.z * x.z + w.w * x.w;
        }
        #pragma unroll
        for (int off = 32; off > 0; off >>= 1) sum += __shfl_down(sum, off);
        if (lane == 0) vmean[b * DD + i] = sum * (1.0f / (float)SS);
    }
}

// K3: orow (LDS) = Wo @ vmean for a 128-wide i-chunk, then broadcast to a 128-row s-chunk.
// 128 blocks x 256 thr; bid = sc*8 + ic; block writes out[b][s0:s0+128][i0:i0+128], both b.
__global__ void matvec2_bcast_kernel(const float* __restrict__ Wo, const float* __restrict__ vmean,
                                     float* __restrict__ out) {
    __shared__ float4 vm4[2 * (DD / 4)];
    __shared__ float4 orow4[2 * 32];         // [b*32 + q4] (= 2x128 floats)
    int t = threadIdx.x, wv = t >> 6, lane = t & 63;
    int bid = blockIdx.x;
    int sc = bid >> 3, ic = bid & 7;
    int i0 = ic * 128, s0 = sc * 128;

    const float4* vg = reinterpret_cast<const float4*>(vmean);
    vm4[t] = vg[t];
    vm4[256 + t] = vg[256 + t];
    __syncthreads();

    float4 x0[4], x1[4];
    #pragma unroll
    for (int p = 0; p < 4; ++p) {
        x0[p] = vm4[lane + p * 64];          // b=0 fragment
        x1[p] = vm4[256 + lane + p * 64];    // b=1 fragment
    }

    float* orow = reinterpret_cast<float*>(orow4);
    #pragma unroll 4
    for (int r = 0; r < 32; ++r) {
        int il = wv * 32 + r;                // 0..127
        int i = i0 + il;
        const float4* Wp = reinterpret_cast<const float4*>(Wo) + (size_t)i * (DD / 4);
        float sb0 = 0.f, sb1 = 0.f;
        #pragma unroll
        for (int p = 0; p < 4; ++p) {
            float4 w = Wp[lane + p * 64];
            sb0 += w.x * x0[p].x + w.y * x0[p].y + w.z * x0[p].z + w.w * x0[p].w;
            sb1 += w.x * x1[p].x + w.y * x1[p].y + w.z * x1[p].z + w.w * x1[p].w;
        }
        #pragma unroll
        for (int off = 32; off > 0; off >>= 1) {
            sb0 += __shfl_down(sb0, off);
            sb1 += __shfl_down(sb1, off);
        }
        if (lane == 0) {
            orow[0 * 128 + il] = sb0;
            orow[1 * 128 + il] = sb1;
        }
    }
    __syncthreads();

    float4* o4 = reinterpret_cast<float4*>(out);
    // 2 b x 128 s x 32 float4 = 8192 stores
    for (int j = t; j < 8192; j += 256) {
        int q4 = j & 31;
        int s = (j >> 5) & 127;
        int b = j >> 12;
        o4[((size_t)(b * SS + s0 + s)) * (DD / 4) + ic * 32 + q4] = orow4[b * 32 + q4];
    }
}

extern "C" void kernel_launch(void* const* d_in, const int* in_sizes, int n_in,
                              void* d_out, int out_size, void* d_ws, size_t ws_size,
                              hipStream_t stream) {
    const float* h  = (const float*)d_in[0];   // [2,2048,1024]
    const float* Wv = (const float*)d_in[3];   // [1024,1024]
    const float* Wo = (const float*)d_in[4];   // [1024,1024]
    float* out = (float*)d_out;                // [2,2048,1024]

    float* partial = (float*)d_ws;             // 128*1024 floats
    float* vmean   = partial + 128 * DD;       // 2048 floats

    colsum_kernel<<<128, 256, 0, stream>>>(h, partial);
    matvec1_kernel<<<32, 256, 0, stream>>>(Wv, partial, vmean);
    matvec2_bcast_kernel<<<128, 256, 0, stream>>>(Wo, vmean, out);
}

// Round 7
// 101.343 us; speedup vs baseline: 2.0659x; 1.1401x over previous
//
#include <hip/hip_runtime.h>

#define BB 2
#define SS 2048
#define DD 1024
#define INNER 1024
#define NCHUNK 128                      // chunks per batch
#define ROWS_PER_CHUNK (SS / NCHUNK)    // 16

// K1: hbar[b,d] = sum_s hidden[b,s,d]  (atomic partial sums, 256 blocks x 16 rows)
__global__ void colsum_kernel(const float* __restrict__ h, float* __restrict__ hbar) {
    int b = blockIdx.x >> 7;             // 0..1
    int chunk = blockIdx.x & 127;        // 0..127
    int t = threadIdx.x;                 // 0..255, each owns 4 consecutive d (float4)
    const float4* hp = reinterpret_cast<const float4*>(h + (size_t)b * SS * DD);
    float4 acc = make_float4(0.f, 0.f, 0.f, 0.f);
    int s0 = chunk * ROWS_PER_CHUNK;
    #pragma unroll 4
    for (int s = s0; s < s0 + ROWS_PER_CHUNK; ++s) {
        float4 v = hp[(size_t)s * (DD / 4) + t];
        acc.x += v.x; acc.y += v.y; acc.z += v.z; acc.w += v.w;
    }
    float* dst = hbar + b * DD + t * 4;
    atomicAdd(dst + 0, acc.x);
    atomicAdd(dst + 1, acc.y);
    atomicAdd(dst + 2, acc.z);
    atomicAdd(dst + 3, acc.w);
}

// K2/K3: y[b*INNER + i] = scale * dot(W[i, :], x[b, :])   (W is [1024,1024] row-major)
// one 64-lane wave per output; 512 blocks x 256 threads = 2048 waves = B*INNER outputs
__global__ void matvec_kernel(const float* __restrict__ W, const float* __restrict__ x,
                              float* __restrict__ y, float scale) {
    int wave = (blockIdx.x * blockDim.x + threadIdx.x) >> 6;  // 0..2047
    int lane = threadIdx.x & 63;
    int b = wave / INNER;
    int i = wave % INNER;
    const float4* Wp = reinterpret_cast<const float4*>(W + (size_t)i * 1024);
    const float4* xp = reinterpret_cast<const float4*>(x + b * 1024);
    float sum = 0.f;
    #pragma unroll
    for (int k4 = lane; k4 < 256; k4 += 64) {
        float4 w = Wp[k4];
        float4 xv = xp[k4];
        sum += w.x * xv.x + w.y * xv.y + w.z * xv.z + w.w * xv.w;
    }
    #pragma unroll
    for (int off = 32; off > 0; off >>= 1) sum += __shfl_down(sum, off);
    if (lane == 0) y[wave] = sum * scale;
}

// K4: out[b,s,:] = orow[b,:]
__global__ void bcast_kernel(const float* __restrict__ row, float* __restrict__ out) {
    const float4* r4 = reinterpret_cast<const float4*>(row);
    float4* o4 = reinterpret_cast<float4*>(out);
    const int total4 = BB * SS * (DD / 4);  // 1,048,576
    for (int i = blockIdx.x * blockDim.x + threadIdx.x; i < total4;
         i += gridDim.x * blockDim.x) {
        int d4 = i & (DD / 4 - 1);      // i % 256
        int b = i >> 19;                // i / 524288
        o4[i] = r4[b * (DD / 4) + d4];
    }
}

extern "C" void kernel_launch(void* const* d_in, const int* in_sizes, int n_in,
                              void* d_out, int out_size, void* d_ws, size_t ws_size,
                              hipStream_t stream) {
    const float* h  = (const float*)d_in[0];   // hidden_states [2,2048,1024]
    const float* Wv = (const float*)d_in[3];   // [1024,1024]
    const float* Wo = (const float*)d_in[4];   // [1024,1024]
    float* out = (float*)d_out;                // [2,2048,1024]

    float* hbar  = (float*)d_ws;               // 2048 floats
    float* vmean = hbar + BB * DD;             // 2048 floats
    float* orow  = vmean + BB * INNER;         // 2048 floats

    hipMemsetAsync(hbar, 0, BB * DD * sizeof(float), stream);
    colsum_kernel<<<BB * NCHUNK, 256, 0, stream>>>(h, hbar);
    matvec_kernel<<<512, 256, 0, stream>>>(Wv, hbar, vmean, 1.0f / (float)SS);
    matvec_kernel<<<512, 256, 0, stream>>>(Wo, vmean, orow, 1.0f);
    bcast_kernel<<<2048, 256, 0, stream>>>(orow, out);
}

// Round 8
// 95.960 us; speedup vs baseline: 2.1818x; 1.0561x over previous
//
#include <hip/hip_runtime.h>

#define BB 2
#define SS 2048
#define DD 1024
#define INNER 1024
#define NCHUNK 64
#define ROWS_PER_CHUNK (SS / NCHUNK)  // 32

// K1: hbar[b,d] = sum_s hidden[b,s,d]  (atomic partial sums over 64 row-chunks)
// 128 blocks: measured best (R0=96.8us); 256 blocks regressed to 101.3us (2x atomics on
// the same 2048 addresses).
__global__ void colsum_kernel(const float* __restrict__ h, float* __restrict__ hbar) {
    int b = blockIdx.x / NCHUNK;
    int chunk = blockIdx.x % NCHUNK;
    int t = threadIdx.x;  // 0..255, each owns 4 consecutive d (float4)
    const float4* hp = reinterpret_cast<const float4*>(h + (size_t)b * SS * DD);
    float4 acc = make_float4(0.f, 0.f, 0.f, 0.f);
    int s0 = chunk * ROWS_PER_CHUNK;
    #pragma unroll 4
    for (int s = s0; s < s0 + ROWS_PER_CHUNK; ++s) {
        float4 v = hp[(size_t)s * (DD / 4) + t];
        acc.x += v.x; acc.y += v.y; acc.z += v.z; acc.w += v.w;
    }
    float* dst = hbar + b * DD + t * 4;
    atomicAdd(dst + 0, acc.x);
    atomicAdd(dst + 1, acc.y);
    atomicAdd(dst + 2, acc.z);
    atomicAdd(dst + 3, acc.w);
}

// K2/K3: y[b*INNER + i] = scale * dot(W[i, :], x[b, :])   (W is [1024,1024] row-major)
// one 64-lane wave per output; 512 blocks x 256 threads = 2048 waves = B*INNER outputs
__global__ void matvec_kernel(const float* __restrict__ W, const float* __restrict__ x,
                              float* __restrict__ y, float scale) {
    int wave = (blockIdx.x * blockDim.x + threadIdx.x) >> 6;  // 0..2047
    int lane = threadIdx.x & 63;
    int b = wave / INNER;
    int i = wave % INNER;
    const float4* Wp = reinterpret_cast<const float4*>(W + (size_t)i * 1024);
    const float4* xp = reinterpret_cast<const float4*>(x + b * 1024);
    float sum = 0.f;
    #pragma unroll
    for (int k4 = lane; k4 < 256; k4 += 64) {
        float4 w = Wp[k4];
        float4 xv = xp[k4];
        sum += w.x * xv.x + w.y * xv.y + w.z * xv.z + w.w * xv.w;
    }
    #pragma unroll
    for (int off = 32; off > 0; off >>= 1) sum += __shfl_down(sum, off);
    if (lane == 0) y[wave] = sum * scale;
}

// K4: out[b,s,:] = orow[b,:]
__global__ void bcast_kernel(const float* __restrict__ row, float* __restrict__ out) {
    const float4* r4 = reinterpret_cast<const float4*>(row);
    float4* o4 = reinterpret_cast<float4*>(out);
    const int total4 = BB * SS * (DD / 4);  // 1,048,576
    for (int i = blockIdx.x * blockDim.x + threadIdx.x; i < total4;
         i += gridDim.x * blockDim.x) {
        int d4 = i & (DD / 4 - 1);      // i % 256
        int b = i >> 19;                // i / 524288
        o4[i] = r4[b * (DD / 4) + d4];
    }
}

extern "C" void kernel_launch(void* const* d_in, const int* in_sizes, int n_in,
                              void* d_out, int out_size, void* d_ws, size_t ws_size,
                              hipStream_t stream) {
    const float* h  = (const float*)d_in[0];   // hidden_states [2,2048,1024]
    const float* Wv = (const float*)d_in[3];   // [1024,1024]
    const float* Wo = (const float*)d_in[4];   // [1024,1024]
    float* out = (float*)d_out;                // [2,2048,1024]

    float* hbar  = (float*)d_ws;               // 2048 floats
    float* vmean = hbar + BB * DD;             // 2048 floats
    float* orow  = vmean + BB * INNER;         // 2048 floats

    hipMemsetAsync(hbar, 0, BB * DD * sizeof(float), stream);
    colsum_kernel<<<BB * NCHUNK, 256, 0, stream>>>(h, hbar);
    matvec_kernel<<<512, 256, 0, stream>>>(Wv, hbar, vmean, 1.0f / (float)SS);
    matvec_kernel<<<512, 256, 0, stream>>>(Wo, vmean, orow, 1.0f);
    bcast_kernel<<<2048, 256, 0, stream>>>(orow, out);
}